// Round 3
// baseline (236.314 us; speedup 1.0000x reference)
//
#include <hip/hip_runtime.h>
#include <math.h>

#define TPB 256
#define ROWS 256           // rows per block
#define CHUNK 16           // feature columns per LDS chunk
#define XS_STRIDE 257      // transposed tile [CHUNK][XS_STRIDE]: row of samples per column

__global__ __launch_bounds__(TPB, 6) void decoder_kernel(
    const float* __restrict__ feat,
    const float* __restrict__ W1, const float* __restrict__ g1, const float* __restrict__ b1,
    const float* __restrict__ W2, const float* __restrict__ g2, const float* __restrict__ b2,
    const float* __restrict__ W3, const float* __restrict__ b3,
    float* __restrict__ out, int N)
{
    // transposed tile: xs[c*XS_STRIDE + r] = feature[row0+r][c0+c]
    __shared__ float xs[CHUNK * XS_STRIDE];   // 16448 B -> LDS allows 9 blocks; VGPR-bound 6

    const int t = threadIdx.x;
    const size_t row0 = (size_t)blockIdx.x * ROWS;
    const size_t myrow = row0 + t;

    // staging decomposition: thread t covers rows sr, sr+64, sr+128, sr+192 at cols sp*4..sp*4+3
    const int sr = t >> 2;     // 0..63
    const int sp = t & 3;      // 0..3

    float4 pre[4];
    {   // prologue: issue chunk 0 loads
#pragma unroll
        for (int i = 0; i < 4; ++i) {
            const size_t gr = row0 + (sr + (i << 6));
            pre[i] = *reinterpret_cast<const float4*>(feat + gr * 128 + 0 + sp * 4);
        }
    }

    float acc[32];
#pragma unroll
    for (int j = 0; j < 32; ++j) acc[j] = 0.f;

    for (int cc = 0; cc < 8; ++cc) {
        const int c0 = cc * CHUNK;
        __syncthreads();   // all readers of the previous chunk are done

        // write staged registers -> transposed LDS tile (scalar b32 writes, <=2-way banks)
#pragma unroll
        for (int i = 0; i < 4; ++i) {
            const int r = sr + (i << 6);
            const float4 v = pre[i];
            xs[(sp * 4 + 0) * XS_STRIDE + r] = v.x;
            xs[(sp * 4 + 1) * XS_STRIDE + r] = v.y;
            xs[(sp * 4 + 2) * XS_STRIDE + r] = v.z;
            xs[(sp * 4 + 3) * XS_STRIDE + r] = v.w;
        }

        // issue NEXT chunk's global loads now; they fly during this chunk's FMA phase
        if (cc < 7) {
            const int cn = c0 + CHUNK;
#pragma unroll
            for (int i = 0; i < 4; ++i) {
                const size_t gr = row0 + (sr + (i << 6));
                pre[i] = *reinterpret_cast<const float4*>(feat + gr * 128 + cn + sp * 4);
            }
        }

        __syncthreads();   // tile visible

        // my row's 16 x-values: lane-consecutive reads, compile-time offsets, conflict-free
        float xr[CHUNK];
#pragma unroll
        for (int c = 0; c < CHUNK; ++c) xr[c] = xs[c * XS_STRIDE + t];

        // j-outer: W1 row slice [c0..c0+15] contiguous -> one s_load_dwordx16 per row
#pragma unroll
        for (int j = 0; j < 32; ++j) {
            const float* __restrict__ wrow = W1 + j * 128 + c0;
            float s = acc[j];
#pragma unroll
            for (int c = 0; c < CHUNK; ++c)
                s = fmaf(xr[c], wrow[c], s);
            acc[j] = s;
        }
    }

    // ---- LayerNorm(32) + leaky ----
    float m = 0.f;
#pragma unroll
    for (int j = 0; j < 32; ++j) m += acc[j];
    m *= (1.f / 32.f);
    float var = 0.f;
#pragma unroll
    for (int j = 0; j < 32; ++j) { const float d = acc[j] - m; var = fmaf(d, d, var); }
    var *= (1.f / 32.f);
    const float rs1 = rsqrtf(var + 1e-5f);

    float z[32];
#pragma unroll
    for (int j = 0; j < 32; ++j) {
        float y = (acc[j] - m) * rs1 * g1[j] + b1[j];
        z[j] = (y >= 0.f) ? y : 0.1f * y;
    }

    // ---- Layer 2: [32] -> [16], W2 rows contiguous ----
    float a2[16];
#pragma unroll
    for (int k = 0; k < 16; ++k) {
        const float* __restrict__ wrow = W2 + k * 32;
        float s = 0.f;
#pragma unroll
        for (int j = 0; j < 32; ++j)
            s = fmaf(z[j], wrow[j], s);
        a2[k] = s;
    }

    // ---- LayerNorm(16) + leaky ----
    float m2 = 0.f;
#pragma unroll
    for (int k = 0; k < 16; ++k) m2 += a2[k];
    m2 *= (1.f / 16.f);
    float v2 = 0.f;
#pragma unroll
    for (int k = 0; k < 16; ++k) { const float d = a2[k] - m2; v2 = fmaf(d, d, v2); }
    v2 *= (1.f / 16.f);
    const float rs2 = rsqrtf(v2 + 1e-5f);

    float z2[16];
#pragma unroll
    for (int k = 0; k < 16; ++k) {
        float y = (a2[k] - m2) * rs2 * g2[k] + b2[k];
        z2[k] = (y >= 0.f) ? y : 0.1f * y;
    }

    // ---- Layer 3: [16] -> [3] + bias ----
    float o[3];
#pragma unroll
    for (int q = 0; q < 3; ++q) {
        const float* __restrict__ wrow = W3 + q * 16;
        float s = b3[q];
#pragma unroll
        for (int k = 0; k < 16; ++k)
            s = fmaf(z2[k], wrow[k], s);
        o[q] = s;
    }

    // ---- normalize ----
    const float nrm = sqrtf(o[0] * o[0] + o[1] * o[1] + o[2] * o[2]);
    const float inv = 1.f / fmaxf(nrm, 1e-12f);

    if (myrow < (size_t)N) {
        out[myrow * 3 + 0] = o[0] * inv;
        out[myrow * 3 + 1] = o[1] * inv;
        out[myrow * 3 + 2] = o[2] * inv;
    }
}

extern "C" void kernel_launch(void* const* d_in, const int* in_sizes, int n_in,
                              void* d_out, int out_size, void* d_ws, size_t ws_size,
                              hipStream_t stream) {
    const float* feat = (const float*)d_in[0];
    const float* W1   = (const float*)d_in[1];
    const float* g1   = (const float*)d_in[2];
    const float* b1   = (const float*)d_in[3];
    const float* W2   = (const float*)d_in[4];
    const float* g2   = (const float*)d_in[5];
    const float* b2   = (const float*)d_in[6];
    const float* W3   = (const float*)d_in[7];
    const float* b3   = (const float*)d_in[8];
    float* out = (float*)d_out;

    const int N = in_sizes[0] / 128;
    const int grid = (N + ROWS - 1) / ROWS;

    decoder_kernel<<<grid, TPB, 0, stream>>>(feat, W1, g1, b1, W2, g2, b2, W3, b3, out, N);
}

// Round 4
// 157.365 us; speedup vs baseline: 1.5017x; 1.5017x over previous
//
#include <hip/hip_runtime.h>
#include <math.h>

typedef short bf16x8 __attribute__((ext_vector_type(8)));   // 8 bf16 in 4 VGPRs
typedef float f32x4  __attribute__((ext_vector_type(4)));

#define TPB 256
#define ROWS 256
#define CSTRIDE 36        // C_lds row stride (floats): rows 16B-aligned, conflict-free
#define BFR_BYTES 24576   // 2 ntiles x 4 ksteps x 3 planes x 64 lanes x 16B
#define PK(lo, hi) (((lo) >> 16) | ((hi) & 0xffff0000u))
#define BOFF(nt, ks, p) ((((nt)*4 + (ks))*3 + (p))*256)      // dword offset of frag block

// plane split: p1 = RNE-bf16, p2/p3 = truncation of residuals. err <= 2^-23|x|
__device__ __forceinline__ void split3A(float x, unsigned &h1, unsigned &h2, unsigned &h3) {
    unsigned u = __float_as_uint(x);
    h1 = (u + 0x7fffu + ((u >> 16) & 1u)) & 0xffff0000u;
    float r1 = x - __uint_as_float(h1);
    h2 = __float_as_uint(r1) & 0xffff0000u;
    float r2 = r1 - __uint_as_float(h2);
    h3 = __float_as_uint(r2);            // unmasked; PK takes the high 16
}
// all-RNE variant for weights (prologue only)
__device__ __forceinline__ void split3W(float x, unsigned &h1, unsigned &h2, unsigned &h3) {
    unsigned u = __float_as_uint(x);
    h1 = (u + 0x7fffu + ((u >> 16) & 1u)) & 0xffff0000u;
    float r1 = x - __uint_as_float(h1);
    unsigned u1 = __float_as_uint(r1);
    h2 = (u1 + 0x7fffu + ((u1 >> 16) & 1u)) & 0xffff0000u;
    float r2 = r1 - __uint_as_float(h2);
    unsigned u2 = __float_as_uint(r2);
    h3 = (u2 + 0x7fffu + ((u2 >> 16) & 1u)) & 0xffff0000u;
}

__global__ __launch_bounds__(TPB, 2) void decoder_kernel(
    const float* __restrict__ feat,
    const float* __restrict__ W1, const float* __restrict__ g1, const float* __restrict__ b1,
    const float* __restrict__ W2, const float* __restrict__ g2, const float* __restrict__ b2,
    const float* __restrict__ W3, const float* __restrict__ b3,
    float* __restrict__ out, int N)
{
    __shared__ __align__(16) unsigned char lds[BFR_BYTES + ROWS * CSTRIDE * 4];  // 61440 B
    unsigned* bfr = (unsigned*)lds;
    float*    Ct  = (float*)(lds + BFR_BYTES);

    const int t = threadIdx.x;
    const int l = t & 63;
    const int w = t >> 6;
    const size_t blk0 = (size_t)blockIdx.x * ROWS;

    // ---------------- prologue: W1 -> 3-plane bf16 B-fragments in LDS -------
    // B(k,n) = W1[n][k]; lane lc: n = lc&15, k = ks*32 + (lc>>4)*8 + e
    for (int c = t; c < 512; c += 256) {
        const int lc = c & 63, ks = (c >> 6) & 3, nt = (c >> 8) & 1;
        const float* wp = W1 + (nt * 16 + (lc & 15)) * 128 + ks * 32 + (lc >> 4) * 8;
        float v[8];
        *(float4*)(v)     = *(const float4*)(wp);
        *(float4*)(v + 4) = *(const float4*)(wp + 4);
        unsigned h1[8], h2[8], h3[8];
#pragma unroll
        for (int i = 0; i < 8; ++i) split3W(v[i], h1[i], h2[i], h3[i]);
        uint4 q1 = {PK(h1[0],h1[1]), PK(h1[2],h1[3]), PK(h1[4],h1[5]), PK(h1[6],h1[7])};
        uint4 q2 = {PK(h2[0],h2[1]), PK(h2[2],h2[3]), PK(h2[4],h2[5]), PK(h2[6],h2[7])};
        uint4 q3 = {PK(h3[0],h3[1]), PK(h3[2],h3[3]), PK(h3[4],h3[5]), PK(h3[6],h3[7])};
        *(uint4*)(bfr + BOFF(nt, ks, 0) + lc * 4) = q1;
        *(uint4*)(bfr + BOFF(nt, ks, 1) + lc * 4) = q2;
        *(uint4*)(bfr + BOFF(nt, ks, 2) + lc * 4) = q3;
    }
    __syncthreads();

    // ---------------- layer 1 via MFMA: 4 row-tiles of 16 per wave ----------
    // A(m,k): lane l: m = l&15, k = ks*32 + (l>>4)*8 + e  -> direct global loads
    const int arow = l & 15;
    const int acol = (l >> 4) * 8;
    float4 buf[2][8];
    {
        size_t rr = blk0 + (size_t)w * 64 + arow;
        if (rr >= (size_t)N) rr = N - 1;
        const float* ap = feat + rr * 128 + acol;
#pragma unroll
        for (int ks = 0; ks < 4; ++ks) {
            buf[0][2 * ks]     = *(const float4*)(ap + ks * 32);
            buf[0][2 * ks + 1] = *(const float4*)(ap + ks * 32 + 4);
        }
    }

#pragma unroll
    for (int j = 0; j < 4; ++j) {
        if (j < 3) {  // prefetch next row-tile; flies under this tile's cvt+MFMA
            size_t rr = blk0 + (size_t)w * 64 + (j + 1) * 16 + arow;
            if (rr >= (size_t)N) rr = N - 1;
            const float* ap = feat + rr * 128 + acol;
#pragma unroll
            for (int ks = 0; ks < 4; ++ks) {
                buf[(j + 1) & 1][2 * ks]     = *(const float4*)(ap + ks * 32);
                buf[(j + 1) & 1][2 * ks + 1] = *(const float4*)(ap + ks * 32 + 4);
            }
        }
        f32x4 acc0 = {0.f, 0.f, 0.f, 0.f};
        f32x4 acc1 = {0.f, 0.f, 0.f, 0.f};
#pragma unroll
        for (int ks = 0; ks < 4; ++ks) {
            float v[8];
            *(float4*)(v)     = buf[j & 1][2 * ks];
            *(float4*)(v + 4) = buf[j & 1][2 * ks + 1];
            unsigned h1[8], h2[8], h3[8];
#pragma unroll
            for (int i = 0; i < 8; ++i) split3A(v[i], h1[i], h2[i], h3[i]);
            uint4 q1 = {PK(h1[0],h1[1]), PK(h1[2],h1[3]), PK(h1[4],h1[5]), PK(h1[6],h1[7])};
            uint4 q2 = {PK(h2[0],h2[1]), PK(h2[2],h2[3]), PK(h2[4],h2[5]), PK(h2[6],h2[7])};
            uint4 q3 = {PK(h3[0],h3[1]), PK(h3[2],h3[3]), PK(h3[4],h3[5]), PK(h3[6],h3[7])};
            bf16x8 a1 = __builtin_bit_cast(bf16x8, q1);
            bf16x8 a2 = __builtin_bit_cast(bf16x8, q2);
            bf16x8 a3 = __builtin_bit_cast(bf16x8, q3);
            bf16x8 B10 = __builtin_bit_cast(bf16x8, *(const uint4*)(bfr + BOFF(0, ks, 0) + l * 4));
            bf16x8 B20 = __builtin_bit_cast(bf16x8, *(const uint4*)(bfr + BOFF(0, ks, 1) + l * 4));
            bf16x8 B30 = __builtin_bit_cast(bf16x8, *(const uint4*)(bfr + BOFF(0, ks, 2) + l * 4));
            bf16x8 B11 = __builtin_bit_cast(bf16x8, *(const uint4*)(bfr + BOFF(1, ks, 0) + l * 4));
            bf16x8 B21 = __builtin_bit_cast(bf16x8, *(const uint4*)(bfr + BOFF(1, ks, 1) + l * 4));
            bf16x8 B31 = __builtin_bit_cast(bf16x8, *(const uint4*)(bfr + BOFF(1, ks, 2) + l * 4));
            // 6 split-products per ntile, all into the same accumulator
            acc0 = __builtin_amdgcn_mfma_f32_16x16x32_bf16(a1, B10, acc0, 0, 0, 0);
            acc1 = __builtin_amdgcn_mfma_f32_16x16x32_bf16(a1, B11, acc1, 0, 0, 0);
            acc0 = __builtin_amdgcn_mfma_f32_16x16x32_bf16(a1, B20, acc0, 0, 0, 0);
            acc1 = __builtin_amdgcn_mfma_f32_16x16x32_bf16(a1, B21, acc1, 0, 0, 0);
            acc0 = __builtin_amdgcn_mfma_f32_16x16x32_bf16(a2, B10, acc0, 0, 0, 0);
            acc1 = __builtin_amdgcn_mfma_f32_16x16x32_bf16(a2, B11, acc1, 0, 0, 0);
            acc0 = __builtin_amdgcn_mfma_f32_16x16x32_bf16(a1, B30, acc0, 0, 0, 0);
            acc1 = __builtin_amdgcn_mfma_f32_16x16x32_bf16(a1, B31, acc1, 0, 0, 0);
            acc0 = __builtin_amdgcn_mfma_f32_16x16x32_bf16(a2, B20, acc0, 0, 0, 0);
            acc1 = __builtin_amdgcn_mfma_f32_16x16x32_bf16(a2, B21, acc1, 0, 0, 0);
            acc0 = __builtin_amdgcn_mfma_f32_16x16x32_bf16(a3, B10, acc0, 0, 0, 0);
            acc1 = __builtin_amdgcn_mfma_f32_16x16x32_bf16(a3, B11, acc1, 0, 0, 0);
        }
        // C/D layout: col = l&15, row = (l>>4)*4 + reg  [m89-verified]
        const int crow = w * 64 + j * 16 + (l >> 4) * 4;
        const int ccol = l & 15;
#pragma unroll
        for (int r = 0; r < 4; ++r) {
            Ct[(crow + r) * CSTRIDE + ccol]      = acc0[r];
            Ct[(crow + r) * CSTRIDE + 16 + ccol] = acc1[r];
        }
    }
    __syncthreads();   // Ct complete

    // ---------------- tail: thread t owns block-row t ------------------------
    float x[32];
#pragma unroll
    for (int c = 0; c < 8; ++c)
        *(float4*)(x + c * 4) = *(const float4*)(Ct + t * CSTRIDE + c * 4);

    float m = 0.f;
#pragma unroll
    for (int j = 0; j < 32; ++j) m += x[j];
    m *= (1.f / 32.f);
    float var = 0.f;
#pragma unroll
    for (int j = 0; j < 32; ++j) { const float d = x[j] - m; var = fmaf(d, d, var); }
    var *= (1.f / 32.f);
    const float rs1 = rsqrtf(var + 1e-5f);

    float z[32];
#pragma unroll
    for (int j = 0; j < 32; ++j) {
        float y = (x[j] - m) * rs1 * g1[j] + b1[j];
        z[j] = (y >= 0.f) ? y : 0.1f * y;
    }

    float a2v[16];
#pragma unroll
    for (int k = 0; k < 16; ++k) {
        const float* __restrict__ wrow = W2 + k * 32;
        float s = 0.f;
#pragma unroll
        for (int j = 0; j < 32; ++j) s = fmaf(z[j], wrow[j], s);
        a2v[k] = s;
    }

    float m2 = 0.f;
#pragma unroll
    for (int k = 0; k < 16; ++k) m2 += a2v[k];
    m2 *= (1.f / 16.f);
    float v2 = 0.f;
#pragma unroll
    for (int k = 0; k < 16; ++k) { const float d = a2v[k] - m2; v2 = fmaf(d, d, v2); }
    v2 *= (1.f / 16.f);
    const float rs2 = rsqrtf(v2 + 1e-5f);

    float z2[16];
#pragma unroll
    for (int k = 0; k < 16; ++k) {
        float y = (a2v[k] - m2) * rs2 * g2[k] + b2[k];
        z2[k] = (y >= 0.f) ? y : 0.1f * y;
    }

    float o[3];
#pragma unroll
    for (int q = 0; q < 3; ++q) {
        const float* __restrict__ wrow = W3 + q * 16;
        float s = b3[q];
#pragma unroll
        for (int k = 0; k < 16; ++k) s = fmaf(z2[k], wrow[k], s);
        o[q] = s;
    }
    const float nrm = sqrtf(o[0]*o[0] + o[1]*o[1] + o[2]*o[2]);
    const float inv = 1.f / fmaxf(nrm, 1e-12f);

    // repack via LDS for coalesced output
    __syncthreads();   // all x-reads of Ct done
    Ct[t * 3 + 0] = o[0] * inv;
    Ct[t * 3 + 1] = o[1] * inv;
    Ct[t * 3 + 2] = o[2] * inv;
    __syncthreads();
    const size_t ob = blk0 * 3;
    const size_t lim = (size_t)N * 3;
#pragma unroll
    for (int i = 0; i < 3; ++i) {
        const size_t gi = ob + t + i * 256;
        if (gi < lim) out[gi] = Ct[t + i * 256];
    }
}

extern "C" void kernel_launch(void* const* d_in, const int* in_sizes, int n_in,
                              void* d_out, int out_size, void* d_ws, size_t ws_size,
                              hipStream_t stream) {
    const float* feat = (const float*)d_in[0];
    const float* W1   = (const float*)d_in[1];
    const float* g1   = (const float*)d_in[2];
    const float* b1   = (const float*)d_in[3];
    const float* W2   = (const float*)d_in[4];
    const float* g2   = (const float*)d_in[5];
    const float* b2   = (const float*)d_in[6];
    const float* W3   = (const float*)d_in[7];
    const float* b3   = (const float*)d_in[8];
    float* out = (float*)d_out;

    const int N = in_sizes[0] / 128;
    const int grid = (N + ROWS - 1) / ROWS;

    decoder_kernel<<<grid, TPB, 0, stream>>>(feat, W1, g1, b1, W2, g2, b2, W3, b3, out, N);
}

// Round 5
// 132.375 us; speedup vs baseline: 1.7852x; 1.1888x over previous
//
#include <hip/hip_runtime.h>
#include <math.h>

typedef short bf16x8 __attribute__((ext_vector_type(8)));   // 8 bf16 in 4 VGPRs
typedef float f32x4  __attribute__((ext_vector_type(4)));

#define TPB 256
#define ROWS 256
#define CSTRIDE 36        // C_lds row stride (floats): rows 16B-aligned
#define BFR_BYTES 16384   // 2 ntiles x 4 ksteps x 2 planes x 64 lanes x 16B
#define PK(lo, hi) (((lo) >> 16) | ((hi) & 0xffff0000u))
#define BOFF(nt, ks, p) ((((nt)*4 + (ks))*2 + (p))*256)      // dword offset of frag block

// 2-plane split for activations: p1 = RNE-bf16(x), p2 = trunc-bf16(x - p1).
// |x - p1 - p2| <= 2^-17 |x|; with 3 of 4 cross products kept, per-term rel err ~2^-15.7
__device__ __forceinline__ void split2A(float x, unsigned &h1, unsigned &h2) {
    unsigned u = __float_as_uint(x);
    h1 = (u + 0x7fffu + ((u >> 16) & 1u)) & 0xffff0000u;
    h2 = __float_as_uint(x - __uint_as_float(h1));   // PK takes the high 16 bits
}
// all-RNE variant for weights (prologue only, cost irrelevant)
__device__ __forceinline__ void split2W(float x, unsigned &h1, unsigned &h2) {
    unsigned u = __float_as_uint(x);
    h1 = (u + 0x7fffu + ((u >> 16) & 1u)) & 0xffff0000u;
    float r1 = x - __uint_as_float(h1);
    unsigned u1 = __float_as_uint(r1);
    h2 = (u1 + 0x7fffu + ((u1 >> 16) & 1u)) & 0xffff0000u;
}

__global__ __launch_bounds__(TPB, 3) void decoder_kernel(
    const float* __restrict__ feat,
    const float* __restrict__ W1, const float* __restrict__ g1, const float* __restrict__ b1,
    const float* __restrict__ W2, const float* __restrict__ g2, const float* __restrict__ b2,
    const float* __restrict__ W3, const float* __restrict__ b3,
    float* __restrict__ out, int N)
{
    __shared__ __align__(16) unsigned char lds[BFR_BYTES + ROWS * CSTRIDE * 4];  // 53248 B -> 3 blocks/CU
    unsigned* bfr = (unsigned*)lds;
    float*    Ct  = (float*)(lds + BFR_BYTES);

    const int t = threadIdx.x;
    const int l = t & 63;
    const int w = t >> 6;
    const size_t blk0 = (size_t)blockIdx.x * ROWS;

    // ---------------- prologue: W1 -> 2-plane bf16 B-fragments in LDS -------
    // B(k,n) = W1[n][k]; lane lc: n = lc&15, k = ks*32 + (lc>>4)*8 + e
    for (int c = t; c < 512; c += 256) {
        const int lc = c & 63, ks = (c >> 6) & 3, nt = (c >> 8) & 1;
        const float* wp = W1 + (nt * 16 + (lc & 15)) * 128 + ks * 32 + (lc >> 4) * 8;
        float v[8];
        *(float4*)(v)     = *(const float4*)(wp);
        *(float4*)(v + 4) = *(const float4*)(wp + 4);
        unsigned h1[8], h2[8];
#pragma unroll
        for (int i = 0; i < 8; ++i) split2W(v[i], h1[i], h2[i]);
        uint4 q1 = {PK(h1[0],h1[1]), PK(h1[2],h1[3]), PK(h1[4],h1[5]), PK(h1[6],h1[7])};
        uint4 q2 = {PK(h2[0],h2[1]), PK(h2[2],h2[3]), PK(h2[4],h2[5]), PK(h2[6],h2[7])};
        *(uint4*)(bfr + BOFF(nt, ks, 0) + lc * 4) = q1;
        *(uint4*)(bfr + BOFF(nt, ks, 1) + lc * 4) = q2;
    }
    __syncthreads();

    // ---------------- layer 1 via MFMA: 4 row-tiles of 16 per wave ----------
    // A(m,k): lane l: m = l&15, k = ks*32 + (l>>4)*8 + e  -> direct global loads
    const int arow = l & 15;
    const int acol = (l >> 4) * 8;
    float4 buf[2][8];
    {
        size_t rr = blk0 + (size_t)w * 64 + arow;
        if (rr >= (size_t)N) rr = N - 1;
        const float* ap = feat + rr * 128 + acol;
#pragma unroll
        for (int ks = 0; ks < 4; ++ks) {
            buf[0][2 * ks]     = *(const float4*)(ap + ks * 32);
            buf[0][2 * ks + 1] = *(const float4*)(ap + ks * 32 + 4);
        }
    }

#pragma unroll
    for (int j = 0; j < 4; ++j) {
        if (j < 3) {  // prefetch next row-tile; flies under this tile's cvt+MFMA
            size_t rr = blk0 + (size_t)w * 64 + (j + 1) * 16 + arow;
            if (rr >= (size_t)N) rr = N - 1;
            const float* ap = feat + rr * 128 + acol;
#pragma unroll
            for (int ks = 0; ks < 4; ++ks) {
                buf[(j + 1) & 1][2 * ks]     = *(const float4*)(ap + ks * 32);
                buf[(j + 1) & 1][2 * ks + 1] = *(const float4*)(ap + ks * 32 + 4);
            }
        }
        f32x4 acc0 = {0.f, 0.f, 0.f, 0.f};
        f32x4 acc1 = {0.f, 0.f, 0.f, 0.f};
#pragma unroll
        for (int ks = 0; ks < 4; ++ks) {
            float v[8];
            *(float4*)(v)     = buf[j & 1][2 * ks];
            *(float4*)(v + 4) = buf[j & 1][2 * ks + 1];
            unsigned h1[8], h2[8];
#pragma unroll
            for (int i = 0; i < 8; ++i) split2A(v[i], h1[i], h2[i]);
            uint4 q1 = {PK(h1[0],h1[1]), PK(h1[2],h1[3]), PK(h1[4],h1[5]), PK(h1[6],h1[7])};
            uint4 q2 = {PK(h2[0],h2[1]), PK(h2[2],h2[3]), PK(h2[4],h2[5]), PK(h2[6],h2[7])};
            bf16x8 a1 = __builtin_bit_cast(bf16x8, q1);
            bf16x8 a2 = __builtin_bit_cast(bf16x8, q2);
            bf16x8 B10 = __builtin_bit_cast(bf16x8, *(const uint4*)(bfr + BOFF(0, ks, 0) + l * 4));
            bf16x8 B20 = __builtin_bit_cast(bf16x8, *(const uint4*)(bfr + BOFF(0, ks, 1) + l * 4));
            bf16x8 B11 = __builtin_bit_cast(bf16x8, *(const uint4*)(bfr + BOFF(1, ks, 0) + l * 4));
            bf16x8 B21 = __builtin_bit_cast(bf16x8, *(const uint4*)(bfr + BOFF(1, ks, 1) + l * 4));
            // 3 split-products per ntile (a2*b2 dropped: ~2^-18 rel)
            acc0 = __builtin_amdgcn_mfma_f32_16x16x32_bf16(a1, B10, acc0, 0, 0, 0);
            acc1 = __builtin_amdgcn_mfma_f32_16x16x32_bf16(a1, B11, acc1, 0, 0, 0);
            acc0 = __builtin_amdgcn_mfma_f32_16x16x32_bf16(a2, B10, acc0, 0, 0, 0);
            acc1 = __builtin_amdgcn_mfma_f32_16x16x32_bf16(a2, B11, acc1, 0, 0, 0);
            acc0 = __builtin_amdgcn_mfma_f32_16x16x32_bf16(a1, B20, acc0, 0, 0, 0);
            acc1 = __builtin_amdgcn_mfma_f32_16x16x32_bf16(a1, B21, acc1, 0, 0, 0);
        }
        // C/D layout: col = l&15, row = (l>>4)*4 + reg  [m89-verified]
        const int crow = w * 64 + j * 16 + (l >> 4) * 4;
        const int ccol = l & 15;
#pragma unroll
        for (int r = 0; r < 4; ++r) {
            Ct[(crow + r) * CSTRIDE + ccol]      = acc0[r];
            Ct[(crow + r) * CSTRIDE + 16 + ccol] = acc1[r];
        }
    }
    __syncthreads();   // Ct complete

    // ---------------- tail: thread t owns block-row t ------------------------
    float x[32];
#pragma unroll
    for (int c = 0; c < 8; ++c)
        *(float4*)(x + c * 4) = *(const float4*)(Ct + t * CSTRIDE + c * 4);

    float m = 0.f;
#pragma unroll
    for (int j = 0; j < 32; ++j) m += x[j];
    m *= (1.f / 32.f);
    float var = 0.f;
#pragma unroll
    for (int j = 0; j < 32; ++j) { const float d = x[j] - m; var = fmaf(d, d, var); }
    var *= (1.f / 32.f);
    const float rs1 = rsqrtf(var + 1e-5f);

    float z[32];
#pragma unroll
    for (int j = 0; j < 32; ++j) {
        float y = (x[j] - m) * rs1 * g1[j] + b1[j];
        z[j] = (y >= 0.f) ? y : 0.1f * y;
    }

    float a2v[16];
#pragma unroll
    for (int k = 0; k < 16; ++k) {
        const float* __restrict__ wrow = W2 + k * 32;
        float s = 0.f;
#pragma unroll
        for (int j = 0; j < 32; ++j) s = fmaf(z[j], wrow[j], s);
        a2v[k] = s;
    }

    float m2 = 0.f;
#pragma unroll
    for (int k = 0; k < 16; ++k) m2 += a2v[k];
    m2 *= (1.f / 16.f);
    float v2 = 0.f;
#pragma unroll
    for (int k = 0; k < 16; ++k) { const float d = a2v[k] - m2; v2 = fmaf(d, d, v2); }
    v2 *= (1.f / 16.f);
    const float rs2 = rsqrtf(v2 + 1e-5f);

    float z2[16];
#pragma unroll
    for (int k = 0; k < 16; ++k) {
        float y = (a2v[k] - m2) * rs2 * g2[k] + b2[k];
        z2[k] = (y >= 0.f) ? y : 0.1f * y;
    }

    float o[3];
#pragma unroll
    for (int q = 0; q < 3; ++q) {
        const float* __restrict__ wrow = W3 + q * 16;
        float s = b3[q];
#pragma unroll
        for (int k = 0; k < 16; ++k) s = fmaf(z2[k], wrow[k], s);
        o[q] = s;
    }
    const float nrm = sqrtf(o[0]*o[0] + o[1]*o[1] + o[2]*o[2]);
    const float inv = 1.f / fmaxf(nrm, 1e-12f);

    // repack via LDS for coalesced output
    __syncthreads();   // all x-reads of Ct done
    Ct[t * 3 + 0] = o[0] * inv;
    Ct[t * 3 + 1] = o[1] * inv;
    Ct[t * 3 + 2] = o[2] * inv;
    __syncthreads();
    const size_t ob = blk0 * 3;
    const size_t lim = (size_t)N * 3;
#pragma unroll
    for (int i = 0; i < 3; ++i) {
        const size_t gi = ob + t + i * 256;
        if (gi < lim) out[gi] = Ct[t + i * 256];
    }
}

extern "C" void kernel_launch(void* const* d_in, const int* in_sizes, int n_in,
                              void* d_out, int out_size, void* d_ws, size_t ws_size,
                              hipStream_t stream) {
    const float* feat = (const float*)d_in[0];
    const float* W1   = (const float*)d_in[1];
    const float* g1   = (const float*)d_in[2];
    const float* b1   = (const float*)d_in[3];
    const float* W2   = (const float*)d_in[4];
    const float* g2   = (const float*)d_in[5];
    const float* b2   = (const float*)d_in[6];
    const float* W3   = (const float*)d_in[7];
    const float* b3   = (const float*)d_in[8];
    float* out = (float*)d_out;

    const int N = in_sizes[0] / 128;
    const int grid = (N + ROWS - 1) / ROWS;

    decoder_kernel<<<grid, TPB, 0, stream>>>(feat, W1, g1, b1, W2, g2, b2, W3, b3, out, N);
}

// Round 6
// 126.512 us; speedup vs baseline: 1.8679x; 1.0463x over previous
//
#include <hip/hip_runtime.h>
#include <math.h>

typedef short bf16x8 __attribute__((ext_vector_type(8)));   // 8 bf16 in 4 VGPRs
typedef float f32x4  __attribute__((ext_vector_type(4)));

#define TPB 256
#define ROWS 256
#define CSTRIDE 36        // Ct row stride (floats): rows 16B-aligned
#define BFR_BYTES 16384   // 2 ntiles x 4 ksteps x 2 planes x 64 lanes x 16B
#define CT_BYTES (ROWS * CSTRIDE * 4)
#define PK(lo, hi) (((lo) >> 16) | ((hi) & 0xffff0000u))
#define BOFF(nt, ks, p) ((((nt)*4 + (ks))*2 + (p))*256)
#define GRID 768          // 3 blocks/CU x 256 CUs; persistent, atomic work queue

// lgkm-only barrier: LDS visibility without draining the global prefetch queue
#define WBAR() do { asm volatile("s_waitcnt lgkmcnt(0)" ::: "memory"); \
                    __builtin_amdgcn_s_barrier(); } while (0)

// 2-plane split: p1 = RNE-bf16(x), p2 = trunc-bf16(x - p1); 3 of 4 cross terms kept
__device__ __forceinline__ void split2A(float x, unsigned &h1, unsigned &h2) {
    unsigned u = __float_as_uint(x);
    h1 = (u + 0x7fffu + ((u >> 16) & 1u)) & 0xffff0000u;
    h2 = __float_as_uint(x - __uint_as_float(h1));   // PK takes high 16 bits
}
__device__ __forceinline__ void split2W(float x, unsigned &h1, unsigned &h2) {
    unsigned u = __float_as_uint(x);
    h1 = (u + 0x7fffu + ((u >> 16) & 1u)) & 0xffff0000u;
    float r1 = x - __uint_as_float(h1);
    unsigned u1 = __float_as_uint(r1);
    h2 = (u1 + 0x7fffu + ((u1 >> 16) & 1u)) & 0xffff0000u;
}

__global__ __launch_bounds__(TPB, 3) void decoder_kernel(
    const float* __restrict__ feat,
    const float* __restrict__ W1, const float* __restrict__ g1, const float* __restrict__ b1,
    const float* __restrict__ W2, const float* __restrict__ g2, const float* __restrict__ b2,
    const float* __restrict__ W3, const float* __restrict__ b3,
    float* __restrict__ out, int N,
    unsigned* __restrict__ ctr, unsigned nchunks)
{
    __shared__ __align__(16) unsigned char lds[BFR_BYTES + CT_BYTES + 16];  // 53264 B -> 3/CU
    unsigned* bfr = (unsigned*)lds;
    float*    Ct  = (float*)(lds + BFR_BYTES);
    volatile unsigned* nxt_sh = (volatile unsigned*)(lds + BFR_BYTES + CT_BYTES);

    const int t = threadIdx.x;
    const int l = t & 63;
    const int w = t >> 6;
    const int arow = l & 15;        // A-fragment: m = l&15
    const int acol = (l >> 4) * 8;  //             k-base = (l>>4)*8

    // ---------------- prologue (ONCE per persistent block) -------------------
    for (int c = t; c < 512; c += 256) {
        const int lc = c & 63, ks = (c >> 6) & 3, nt = (c >> 8) & 1;
        const float* wp = W1 + (nt * 16 + (lc & 15)) * 128 + ks * 32 + (lc >> 4) * 8;
        float v[8];
        *(float4*)(v)     = *(const float4*)(wp);
        *(float4*)(v + 4) = *(const float4*)(wp + 4);
        unsigned h1[8], h2[8];
#pragma unroll
        for (int i = 0; i < 8; ++i) split2W(v[i], h1[i], h2[i]);
        uint4 q1 = {PK(h1[0],h1[1]), PK(h1[2],h1[3]), PK(h1[4],h1[5]), PK(h1[6],h1[7])};
        uint4 q2 = {PK(h2[0],h2[1]), PK(h2[2],h2[3]), PK(h2[4],h2[5]), PK(h2[6],h2[7])};
        *(uint4*)(bfr + BOFF(nt, ks, 0) + lc * 4) = q1;
        *(uint4*)(bfr + BOFF(nt, ks, 1) + lc * 4) = q2;
    }
    if (t == 0) *nxt_sh = atomicAdd(ctr, 1u);
    __syncthreads();                 // bfr + first chunk id ready
    unsigned cur = *nxt_sh;

    float4 buf[2][8];
    if (cur < nchunks) {             // preload tile 0 of first chunk
        size_t rr = (size_t)cur * ROWS + (size_t)w * 64 + arow;
        if (rr >= (size_t)N) rr = N - 1;
        const float* ap = feat + rr * 128 + acol;
#pragma unroll
        for (int ks = 0; ks < 4; ++ks) {
            buf[0][2 * ks]     = *(const float4*)(ap + ks * 32);
            buf[0][2 * ks + 1] = *(const float4*)(ap + ks * 32 + 4);
        }
    }

    while (cur < nchunks) {
        const size_t blk0 = (size_t)cur * ROWS;

        // ---------------- layer 1 via MFMA: 4 row-tiles of 16 per wave ------
#pragma unroll
        for (int j = 0; j < 4; ++j) {
            if (j == 1 && t == 0) *nxt_sh = atomicAdd(ctr, 1u);  // grab next chunk early
            if (j < 3) {  // prefetch next row-tile
                size_t rr = blk0 + (size_t)w * 64 + (j + 1) * 16 + arow;
                if (rr >= (size_t)N) rr = N - 1;
                const float* ap = feat + rr * 128 + acol;
#pragma unroll
                for (int ks = 0; ks < 4; ++ks) {
                    buf[(j + 1) & 1][2 * ks]     = *(const float4*)(ap + ks * 32);
                    buf[(j + 1) & 1][2 * ks + 1] = *(const float4*)(ap + ks * 32 + 4);
                }
            }
            f32x4 acc0 = {0.f, 0.f, 0.f, 0.f};
            f32x4 acc1 = {0.f, 0.f, 0.f, 0.f};
#pragma unroll
            for (int ks = 0; ks < 4; ++ks) {
                float v[8];
                *(float4*)(v)     = buf[j & 1][2 * ks];
                *(float4*)(v + 4) = buf[j & 1][2 * ks + 1];
                unsigned h1[8], h2[8];
#pragma unroll
                for (int i = 0; i < 8; ++i) split2A(v[i], h1[i], h2[i]);
                uint4 q1 = {PK(h1[0],h1[1]), PK(h1[2],h1[3]), PK(h1[4],h1[5]), PK(h1[6],h1[7])};
                uint4 q2 = {PK(h2[0],h2[1]), PK(h2[2],h2[3]), PK(h2[4],h2[5]), PK(h2[6],h2[7])};
                bf16x8 a1 = __builtin_bit_cast(bf16x8, q1);
                bf16x8 a2 = __builtin_bit_cast(bf16x8, q2);
                bf16x8 B10 = __builtin_bit_cast(bf16x8, *(const uint4*)(bfr + BOFF(0, ks, 0) + l * 4));
                bf16x8 B20 = __builtin_bit_cast(bf16x8, *(const uint4*)(bfr + BOFF(0, ks, 1) + l * 4));
                bf16x8 B11 = __builtin_bit_cast(bf16x8, *(const uint4*)(bfr + BOFF(1, ks, 0) + l * 4));
                bf16x8 B21 = __builtin_bit_cast(bf16x8, *(const uint4*)(bfr + BOFF(1, ks, 1) + l * 4));
                acc0 = __builtin_amdgcn_mfma_f32_16x16x32_bf16(a1, B10, acc0, 0, 0, 0);
                acc1 = __builtin_amdgcn_mfma_f32_16x16x32_bf16(a1, B11, acc1, 0, 0, 0);
                acc0 = __builtin_amdgcn_mfma_f32_16x16x32_bf16(a2, B10, acc0, 0, 0, 0);
                acc1 = __builtin_amdgcn_mfma_f32_16x16x32_bf16(a2, B11, acc1, 0, 0, 0);
                acc0 = __builtin_amdgcn_mfma_f32_16x16x32_bf16(a1, B20, acc0, 0, 0, 0);
                acc1 = __builtin_amdgcn_mfma_f32_16x16x32_bf16(a1, B21, acc1, 0, 0, 0);
            }
            // C/D layout: col = l&15, row = (l>>4)*4 + reg
            const int crow = w * 64 + j * 16 + (l >> 4) * 4;
            const int ccol = l & 15;
#pragma unroll
            for (int r = 0; r < 4; ++r) {
                Ct[(crow + r) * CSTRIDE + ccol]      = acc0[r];
                Ct[(crow + r) * CSTRIDE + 16 + ccol] = acc1[r];
            }
        }
        WBAR();   // Ct complete + nxt_sh visible (global prefetches stay in flight)

        float x[32];
#pragma unroll
        for (int c = 0; c < 8; ++c)
            *(float4*)(x + c * 4) = *(const float4*)(Ct + t * CSTRIDE + c * 4);
        const unsigned nxt = *nxt_sh;
        WBAR();   // all Ct reads retired; Ct may be overwritten next iteration

        if (nxt < nchunks) {   // next chunk's tile 0 flies under the tail
            size_t rr = (size_t)nxt * ROWS + (size_t)w * 64 + arow;
            if (rr >= (size_t)N) rr = N - 1;
            const float* ap = feat + rr * 128 + acol;
#pragma unroll
            for (int ks = 0; ks < 4; ++ks) {
                buf[0][2 * ks]     = *(const float4*)(ap + ks * 32);
                buf[0][2 * ks + 1] = *(const float4*)(ap + ks * 32 + 4);
            }
        }

        // ---------------- tail: thread t owns row blk0 + t --------------------
        float m = 0.f;
#pragma unroll
        for (int j = 0; j < 32; ++j) m += x[j];
        m *= (1.f / 32.f);
        float var = 0.f;
#pragma unroll
        for (int j = 0; j < 32; ++j) { const float d = x[j] - m; var = fmaf(d, d, var); }
        var *= (1.f / 32.f);
        const float rs1 = rsqrtf(var + 1e-5f);

        float z[32];
#pragma unroll
        for (int j = 0; j < 32; ++j) {
            float y = (x[j] - m) * rs1 * g1[j] + b1[j];
            z[j] = (y >= 0.f) ? y : 0.1f * y;
        }

        float a2v[16];
#pragma unroll
        for (int k = 0; k < 16; ++k) {
            const float* __restrict__ wrow = W2 + k * 32;
            float s = 0.f;
#pragma unroll
            for (int j = 0; j < 32; ++j) s = fmaf(z[j], wrow[j], s);
            a2v[k] = s;
        }

        float m2 = 0.f;
#pragma unroll
        for (int k = 0; k < 16; ++k) m2 += a2v[k];
        m2 *= (1.f / 16.f);
        float v2 = 0.f;
#pragma unroll
        for (int k = 0; k < 16; ++k) { const float d = a2v[k] - m2; v2 = fmaf(d, d, v2); }
        v2 *= (1.f / 16.f);
        const float rs2 = rsqrtf(v2 + 1e-5f);

        float z2[16];
#pragma unroll
        for (int k = 0; k < 16; ++k) {
            float y = (a2v[k] - m2) * rs2 * g2[k] + b2[k];
            z2[k] = (y >= 0.f) ? y : 0.1f * y;
        }

        float o[3];
#pragma unroll
        for (int q = 0; q < 3; ++q) {
            const float* __restrict__ wrow = W3 + q * 16;
            float s = b3[q];
#pragma unroll
            for (int k = 0; k < 16; ++k) s = fmaf(z2[k], wrow[k], s);
            o[q] = s;
        }
        const float nrm = sqrtf(o[0]*o[0] + o[1]*o[1] + o[2]*o[2]);
        const float inv = 1.f / fmaxf(nrm, 1e-12f);

        const size_t myrow = blk0 + t;
        if (myrow < (size_t)N) {
            out[myrow * 3 + 0] = o[0] * inv;
            out[myrow * 3 + 1] = o[1] * inv;
            out[myrow * 3 + 2] = o[2] * inv;
        }

        cur = nxt;
    }
}

extern "C" void kernel_launch(void* const* d_in, const int* in_sizes, int n_in,
                              void* d_out, int out_size, void* d_ws, size_t ws_size,
                              hipStream_t stream) {
    const float* feat = (const float*)d_in[0];
    const float* W1   = (const float*)d_in[1];
    const float* g1   = (const float*)d_in[2];
    const float* b1   = (const float*)d_in[3];
    const float* W2   = (const float*)d_in[4];
    const float* g2   = (const float*)d_in[5];
    const float* b2   = (const float*)d_in[6];
    const float* W3   = (const float*)d_in[7];
    const float* b3   = (const float*)d_in[8];
    float* out = (float*)d_out;

    const int N = in_sizes[0] / 128;
    const unsigned nchunks = (unsigned)((N + ROWS - 1) / ROWS);
    unsigned* ctr = (unsigned*)d_ws;

    hipMemsetAsync(ctr, 0, sizeof(unsigned), stream);   // stream-ordered, graph-safe
    decoder_kernel<<<GRID, TPB, 0, stream>>>(feat, W1, g1, b1, W2, g2, b2, W3, b3,
                                             out, N, ctr, nchunks);
}